// Round 2
// baseline (95.207 us; speedup 1.0000x reference)
//
#include <hip/hip_runtime.h>

// Problem constants (from reference)
#define B_    8
#define H_    512
#define W_    512
#define KS_   3
#define KK_   9
#define COUT_ 3
#define HO_   510
#define WO_   510
#define TPR_  128   // threads per row; each thread does 4 consecutive wo pixels

typedef float f2 __attribute__((ext_vector_type(2)));

__global__ __launch_bounds__(256) void dcn_fwd_kernel(
    const float* __restrict__ x,       // [B,1,H,W]
    const float* __restrict__ offset,  // [B,2*KK,HO,WO]
    const float* __restrict__ mask,    // [B,KK,HO,WO]
    const float* __restrict__ weight,  // [COUT,1,KS,KS]
    const float* __restrict__ bias,    // [COUT]
    float* __restrict__ out)           // [B,COUT,HO,WO]
{
    const int total = B_ * HO_ * TPR_;
    const int idx = blockIdx.x * blockDim.x + threadIdx.x;
    if (idx >= total) return;

    const int j = idx % TPR_;
    int t = idx / TPR_;
    const int ho = t % HO_;
    const int b  = t / HO_;
    int wo0 = 4 * j;
    if (wo0 > WO_ - 4) wo0 = WO_ - 4;   // tail thread overlaps prev by 2 px (benign)

    const size_t planeO = (size_t)HO_ * WO_;
    const float* xb = x + (size_t)b * (H_ * W_);
    const size_t pix = (size_t)ho * WO_ + (size_t)wo0;   // even -> 8B aligned
    const float* offb = offset + (size_t)b * (2 * KK_) * planeO + pix;
    const float* mb   = mask   + (size_t)b * KK_ * planeO       + pix;

    // weights/bias -> registers (uniform address: scalarized broadcast loads)
    float w0[KK_], w1[KK_], w2[KK_];
    #pragma unroll
    for (int k = 0; k < KK_; ++k) {
        w0[k] = weight[0 * KK_ + k];
        w1[k] = weight[1 * KK_ + k];
        w2[k] = weight[2 * KK_ + k];
    }
    const float b0 = bias[0], b1 = bias[1], b2 = bias[2];

    float acc0[4] = {0.f, 0.f, 0.f, 0.f};
    float acc1[4] = {0.f, 0.f, 0.f, 0.f};
    float acc2[4] = {0.f, 0.f, 0.f, 0.f};

    #pragma unroll
    for (int kk = 0; kk < KK_; ++kk) {
        const float* dyp = offb + (size_t)(2 * kk) * planeO;
        const float* dxp = dyp + planeO;
        const float* mp  = mb + (size_t)kk * planeO;

        // nontemporal stream loads: don't evict x from L2
        const f2 dyA = __builtin_nontemporal_load((const f2*)dyp);
        const f2 dyB = __builtin_nontemporal_load((const f2*)(dyp + 2));
        const f2 dxA = __builtin_nontemporal_load((const f2*)dxp);
        const f2 dxB = __builtin_nontemporal_load((const f2*)(dxp + 2));
        const f2 mA  = __builtin_nontemporal_load((const f2*)mp);
        const f2 mB  = __builtin_nontemporal_load((const f2*)(mp + 2));

        const float dy[4] = {dyA.x, dyA.y, dyB.x, dyB.y};
        const float dx[4] = {dxA.x, dxA.y, dxB.x, dxB.y};
        const float mv[4] = {mA.x,  mA.y,  mB.x,  mB.y};

        const float baseY = (float)(ho  + kk / KS_);
        const float baseX0 = (float)(wo0 + kk % KS_);

        #pragma unroll
        for (int p = 0; p < 4; ++p) {
            const float py = baseY + dy[p];
            const float px = baseX0 + (float)p + dx[p];

            const float y0f = floorf(py);
            const float x0f = floorf(px);
            const float ly  = py - y0f;
            const float lx  = px - x0f;
            const float y1f = y0f + 1.0f;
            const float x1f = x0f + 1.0f;

            // validity on UNCLIPPED float corner coords (reference semantics)
            const float vy0 = (y0f >= 0.0f && y0f <= (float)(H_ - 1)) ? 1.0f : 0.0f;
            const float vy1 = (y1f >= 0.0f && y1f <= (float)(H_ - 1)) ? 1.0f : 0.0f;
            const float vx0 = (x0f >= 0.0f && x0f <= (float)(W_ - 1)) ? 1.0f : 0.0f;
            const float vx1 = (x1f >= 0.0f && x1f <= (float)(W_ - 1)) ? 1.0f : 0.0f;

            int yi0 = (int)y0f; yi0 = yi0 < 0 ? 0 : (yi0 > H_ - 1 ? H_ - 1 : yi0);
            int yi1 = (int)y1f; yi1 = yi1 < 0 ? 0 : (yi1 > H_ - 1 ? H_ - 1 : yi1);
            int xi0 = (int)x0f; xi0 = xi0 < 0 ? 0 : (xi0 > W_ - 1 ? W_ - 1 : xi0);
            int xi1 = (int)x1f; xi1 = xi1 < 0 ? 0 : (xi1 > W_ - 1 ? W_ - 1 : xi1);

            const float v00 = xb[yi0 * W_ + xi0] * (vy0 * vx0);
            const float v01 = xb[yi0 * W_ + xi1] * (vy0 * vx1);
            const float v10 = xb[yi1 * W_ + xi0] * (vy1 * vx0);
            const float v11 = xb[yi1 * W_ + xi1] * (vy1 * vx1);

            const float val = v00 * (1.0f - ly) * (1.0f - lx)
                            + v01 * (1.0f - ly) * lx
                            + v10 * ly * (1.0f - lx)
                            + v11 * ly * lx;

            const float s = val * mv[p];
            acc0[p] = fmaf(w0[kk], s, acc0[p]);
            acc1[p] = fmaf(w1[kk], s, acc1[p]);
            acc2[p] = fmaf(w2[kk], s, acc2[p]);
        }
    }

    const size_t obase = (size_t)b * COUT_ * planeO + pix;
    f2 o0A = {acc0[0] + b0, acc0[1] + b0};
    f2 o0B = {acc0[2] + b0, acc0[3] + b0};
    f2 o1A = {acc1[0] + b1, acc1[1] + b1};
    f2 o1B = {acc1[2] + b1, acc1[3] + b1};
    f2 o2A = {acc2[0] + b2, acc2[1] + b2};
    f2 o2B = {acc2[2] + b2, acc2[3] + b2};
    *(f2*)(out + obase)                   = o0A;
    *(f2*)(out + obase + 2)               = o0B;
    *(f2*)(out + obase + planeO)          = o1A;
    *(f2*)(out + obase + planeO + 2)      = o1B;
    *(f2*)(out + obase + 2 * planeO)      = o2A;
    *(f2*)(out + obase + 2 * planeO + 2)  = o2B;
}

extern "C" void kernel_launch(void* const* d_in, const int* in_sizes, int n_in,
                              void* d_out, int out_size, void* d_ws, size_t ws_size,
                              hipStream_t stream) {
    const float* x      = (const float*)d_in[0];
    const float* offset = (const float*)d_in[1];
    const float* mask   = (const float*)d_in[2];
    const float* weight = (const float*)d_in[3];
    const float* bias   = (const float*)d_in[4];
    float* out = (float*)d_out;

    const int total = B_ * HO_ * TPR_;
    const int block = 256;
    const int grid  = (total + block - 1) / block;
    dcn_fwd_kernel<<<grid, block, 0, stream>>>(x, offset, mask, weight, bias, out);
}

// Round 5
// 68.611 us; speedup vs baseline: 1.3876x; 1.3876x over previous
//
#include <hip/hip_runtime.h>

// Problem constants (from reference)
#define B_    8
#define H_    512
#define W_    512
#define KS_   3
#define KK_   9
#define COUT_ 3
#define HO_   510
#define WO_   510
#define TPR_  256   // threads per row; each thread does 2 consecutive wo pixels

typedef float f2 __attribute__((ext_vector_type(2)));

__global__ __launch_bounds__(256) void dcn_fwd_kernel(
    const float* __restrict__ x,       // [B,1,H,W]
    const float* __restrict__ offset,  // [B,2*KK,HO,WO]
    const float* __restrict__ mask,    // [B,KK,HO,WO]
    const float* __restrict__ weight,  // [COUT,1,KS,KS]
    const float* __restrict__ bias,    // [COUT]
    float* __restrict__ out)           // [B,COUT,HO,WO]
{
    const int total = B_ * HO_ * TPR_;
    const int idx = blockIdx.x * blockDim.x + threadIdx.x;
    if (idx >= total) return;

    const int j = idx & (TPR_ - 1);       // 0..255
    const int t = idx >> 8;               // b*HO + ho
    const int ho = t % HO_;
    const int b  = t / HO_;
    int wo0 = 2 * j;
    if (wo0 > WO_ - 2) wo0 = WO_ - 2;     // j=255 duplicates wo0=508 (benign)

    const size_t planeO = (size_t)HO_ * WO_;
    const float* xb = x + (size_t)b * (H_ * W_);
    const size_t pix = (size_t)ho * WO_ + (size_t)wo0;   // even -> 8B aligned
    const float* offb = offset + (size_t)b * (2 * KK_) * planeO + pix;
    const float* mb   = mask   + (size_t)b * KK_ * planeO       + pix;

    // weights/bias: uniform addresses -> scalar (SGPR) broadcast loads
    float w0[KK_], w1[KK_], w2[KK_];
    #pragma unroll
    for (int k = 0; k < KK_; ++k) {
        w0[k] = weight[0 * KK_ + k];
        w1[k] = weight[1 * KK_ + k];
        w2[k] = weight[2 * KK_ + k];
    }
    const float b0 = bias[0], b1 = bias[1], b2 = bias[2];

    float acc0[2] = {0.f, 0.f};
    float acc1[2] = {0.f, 0.f};
    float acc2[2] = {0.f, 0.f};

    #pragma unroll
    for (int kk = 0; kk < KK_; ++kk) {
        const float* dyp = offb + (size_t)(2 * kk) * planeO;
        const float* dxp = dyp + planeO;
        const float* mp  = mb + (size_t)kk * planeO;

        const f2 dyv = *(const f2*)dyp;
        const f2 dxv = *(const f2*)dxp;
        const f2 mv  = *(const f2*)mp;

        const float baseY  = (float)(ho  + kk / KS_);
        const float baseX0 = (float)(wo0 + kk % KS_);

        #pragma unroll
        for (int p = 0; p < 2; ++p) {
            const float py = baseY + dyv[p];
            const float px = baseX0 + (float)p + dxv[p];

            const float y0f = floorf(py);
            const float x0f = floorf(px);
            const float ly  = py - y0f;
            const float lx  = px - x0f;
            const float y1f = y0f + 1.0f;
            const float x1f = x0f + 1.0f;

            // validity on UNCLIPPED float corner coords (reference semantics)
            const float vy0 = (y0f >= 0.0f && y0f <= (float)(H_ - 1)) ? 1.0f : 0.0f;
            const float vy1 = (y1f >= 0.0f && y1f <= (float)(H_ - 1)) ? 1.0f : 0.0f;
            const float vx0 = (x0f >= 0.0f && x0f <= (float)(W_ - 1)) ? 1.0f : 0.0f;
            const float vx1 = (x1f >= 0.0f && x1f <= (float)(W_ - 1)) ? 1.0f : 0.0f;

            int yi0 = (int)y0f; yi0 = yi0 < 0 ? 0 : (yi0 > H_ - 1 ? H_ - 1 : yi0);
            int yi1 = (int)y1f; yi1 = yi1 < 0 ? 0 : (yi1 > H_ - 1 ? H_ - 1 : yi1);
            int xi0 = (int)x0f; xi0 = xi0 < 0 ? 0 : (xi0 > W_ - 1 ? W_ - 1 : xi0);
            int xi1 = (int)x1f; xi1 = xi1 < 0 ? 0 : (xi1 > W_ - 1 ? W_ - 1 : xi1);

            const float v00 = xb[yi0 * W_ + xi0] * (vy0 * vx0);
            const float v01 = xb[yi0 * W_ + xi1] * (vy0 * vx1);
            const float v10 = xb[yi1 * W_ + xi0] * (vy1 * vx0);
            const float v11 = xb[yi1 * W_ + xi1] * (vy1 * vx1);

            const float val = v00 * (1.0f - ly) * (1.0f - lx)
                            + v01 * (1.0f - ly) * lx
                            + v10 * ly * (1.0f - lx)
                            + v11 * ly * lx;

            const float s = val * mv[p];
            acc0[p] = fmaf(w0[kk], s, acc0[p]);
            acc1[p] = fmaf(w1[kk], s, acc1[p]);
            acc2[p] = fmaf(w2[kk], s, acc2[p]);
        }
    }

    const size_t obase = (size_t)b * COUT_ * planeO + pix;
    f2 o0 = {acc0[0] + b0, acc0[1] + b0};
    f2 o1 = {acc1[0] + b1, acc1[1] + b1};
    f2 o2 = {acc2[0] + b2, acc2[1] + b2};
    *(f2*)(out + obase)              = o0;
    *(f2*)(out + obase + planeO)     = o1;
    *(f2*)(out + obase + 2 * planeO) = o2;
}

extern "C" void kernel_launch(void* const* d_in, const int* in_sizes, int n_in,
                              void* d_out, int out_size, void* d_ws, size_t ws_size,
                              hipStream_t stream) {
    const float* x      = (const float*)d_in[0];
    const float* offset = (const float*)d_in[1];
    const float* mask   = (const float*)d_in[2];
    const float* weight = (const float*)d_in[3];
    const float* bias   = (const float*)d_in[4];
    float* out = (float*)d_out;

    const int total = B_ * HO_ * TPR_;
    const int block = 256;
    const int grid  = (total + block - 1) / block;
    dcn_fwd_kernel<<<grid, block, 0, stream>>>(x, offset, mask, weight, bias, out);
}